// Round 1
// baseline (373.894 us; speedup 1.0000x reference)
//
#include <hip/hip_runtime.h>

#define N_PIX 50176
#define W_IMG 224

typedef __attribute__((ext_vector_type(8))) short s8v;   // 8 bf16
typedef __attribute__((ext_vector_type(4))) float f4v;
typedef __attribute__((ext_vector_type(4))) unsigned int u4v;

__device__ __forceinline__ short f2bf(float f) {
    __bf16 h = (__bf16)f;
    return __builtin_bit_cast(short, h);
}
__device__ __forceinline__ float bf2f(unsigned short s) {
    unsigned int u = ((unsigned int)s) << 16;
    return __builtin_bit_cast(float, u);
}

// ---------------------------------------------------------------------------
// K0: fold weights.  Wct[n][k] = (w_obs2 @ w_ol1_top)^T  (bf16, [128][128])
//     wol2t[n][k]   = w_ol2^T                            (bf16, [64][128])
//     bias_c[h]     = b_ol1[h] + sum_e b_obs2[e]*w_ol1[e][h]
// ---------------------------------------------------------------------------
__global__ void k0_weights(const float* __restrict__ w_obs2, const float* __restrict__ b_obs2,
                           const float* __restrict__ w_ol1, const float* __restrict__ b_ol1,
                           const float* __restrict__ w_ol2,
                           unsigned short* __restrict__ Wct,
                           unsigned short* __restrict__ wol2t,
                           float* __restrict__ bias_c) {
    int bid = blockIdx.x, t = threadIdx.x;
    if (bid < 64) {
        int lin = bid * 256 + t;          // 16384 elements
        int n = lin >> 7, k = lin & 127;
        float s = 0.f;
        #pragma unroll
        for (int e = 0; e < 64; ++e) s = fmaf(w_obs2[k * 64 + e], w_ol1[e * 128 + n], s);
        Wct[n * 128 + k] = (unsigned short)f2bf(s);
    } else if (bid < 96) {
        int lin = (bid - 64) * 256 + t;   // 8192 elements
        int n = lin >> 7, k = lin & 127;
        wol2t[n * 128 + k] = (unsigned short)f2bf(w_ol2[k * 64 + n]);
    } else {
        if (t < 128) {
            float s = b_ol1[t];
            #pragma unroll
            for (int e = 0; e < 64; ++e) s = fmaf(b_obs2[e], w_ol1[e * 128 + t], s);
            bias_c[t] = s;
        }
    }
}

// ---------------------------------------------------------------------------
// K1: per-pixel loc MLP folded through w_ol1 bottom half.
//     eml2[n][h] = sum_e em_loc[n][e] * w_ol1[64+e][h]     (bf16, [N][128])
// ---------------------------------------------------------------------------
__global__ __launch_bounds__(256) void k1_loc(
        const float* __restrict__ w_loc1, const float* __restrict__ b_loc1,
        const float* __restrict__ w_loc2, const float* __restrict__ b_loc2,
        const float* __restrict__ w_ol1,
        unsigned short* __restrict__ eml2) {
    int n = blockIdx.x * 256 + threadIdx.x;
    int iy = n / W_IMG, ix = n % W_IMG;
    float y = -10.f + (20.f / 223.f) * (float)iy;
    float x = -10.f + (20.f / 223.f) * (float)ix;

    float em[64];
    #pragma unroll
    for (int e = 0; e < 64; ++e) em[e] = b_loc2[e];
    for (int h = 0; h < 128; ++h) {
        float hv = fmaf(y, w_loc1[h], fmaf(x, w_loc1[128 + h], b_loc1[h]));
        hv = fmaxf(hv, 0.f);
        #pragma unroll
        for (int e = 0; e < 64; ++e) em[e] = fmaf(hv, w_loc2[h * 64 + e], em[e]);
    }
    for (int h2 = 0; h2 < 128; ++h2) {
        float s0 = 0.f, s1 = 0.f, s2 = 0.f, s3 = 0.f;
        #pragma unroll
        for (int e = 0; e < 64; e += 4) {
            s0 = fmaf(em[e + 0], w_ol1[(64 + e + 0) * 128 + h2], s0);
            s1 = fmaf(em[e + 1], w_ol1[(64 + e + 1) * 128 + h2], s1);
            s2 = fmaf(em[e + 2], w_ol1[(64 + e + 2) * 128 + h2], s2);
            s3 = fmaf(em[e + 3], w_ol1[(64 + e + 3) * 128 + h2], s3);
        }
        eml2[(size_t)n * 128 + h2] = (unsigned short)f2bf((s0 + s1) + (s2 + s3));
    }
}

// ---------------------------------------------------------------------------
// K2: fused main kernel. Per 64-row tile:
//   S1 (VALU): hidden_obs = relu(obs @ w_obs1 + b_obs1) -> bufA (bf16, swz)
//              copy eml2 tile -> bufC
//   S3 (MFMA): hidden_ol = relu(bufA @ Wc + bufC + bias_c) -> bufB
//   S4 (MFMA): out = bufB @ w_ol2 + b_ol2; softplus; accumulate col partials
// B operands (Wc, w_ol2^T) live in registers for the whole block.
// ---------------------------------------------------------------------------
#define SWZ(r, cb) ((((r) * 256) + (cb)) ^ (((r) & 15) << 4))

__global__ __launch_bounds__(512, 2) void k2_main(
        const float* __restrict__ images,
        const float* __restrict__ w_obs1, const float* __restrict__ b_obs1,
        const unsigned short* __restrict__ Wct, const float* __restrict__ bias_c,
        const unsigned short* __restrict__ wol2t, const float* __restrict__ b_ol2,
        const unsigned short* __restrict__ eml2,
        float* __restrict__ part)      // [32][8][64]
{
    __shared__ char bufA[64 * 256];
    __shared__ char bufB[64 * 256];
    __shared__ char bufC[64 * 256];
    __shared__ float ws1[3 * 128];
    __shared__ float bs1[128];
    __shared__ float red[8][32];

    const int t = threadIdx.x;
    const int w = t >> 6, l = t & 63;
    const int bx = blockIdx.x, b = blockIdx.y;
    const int l15 = l & 15, lg = l >> 4;
    const int mstrip = w & 3;          // M tile (16 rows) for S3/S4
    const int nhalf  = w >> 2;         // 0/1: which half of N columns
    const int m0 = mstrip * 16;

    if (t < 384) ws1[t] = w_obs1[t];
    else bs1[t - 384] = b_obs1[t - 384];

    // persistent B fragments (registers)
    s8v wc[4][4];                      // Wc: [ntile][kstep]
    #pragma unroll
    for (int nt = 0; nt < 4; ++nt) {
        int ncol = (nhalf * 4 + nt) * 16 + l15;
        #pragma unroll
        for (int ks = 0; ks < 4; ++ks)
            wc[nt][ks] = *(const s8v*)(Wct + ncol * 128 + ks * 32 + lg * 8);
    }
    s8v w2[2][4];                      // w_ol2^T
    float bias4[2];
    #pragma unroll
    for (int i = 0; i < 2; ++i) {
        int ncol = (nhalf * 2 + i) * 16 + l15;
        #pragma unroll
        for (int ks = 0; ks < 4; ++ks)
            w2[i][ks] = *(const s8v*)(wol2t + ncol * 128 + ks * 32 + lg * 8);
        bias4[i] = b_ol2[ncol];
    }
    float bias3[4];
    #pragma unroll
    for (int nt = 0; nt < 4; ++nt) bias3[nt] = bias_c[(nhalf * 4 + nt) * 16 + l15];

    float sp0 = 0.f, sp1 = 0.f;

    const int s1r = t >> 3;            // 0..63 : row for stage1 / eml2 copy
    const int s1h = (t & 7) * 16;      // 16 hidden units per thread
    const size_t imgbase = (size_t)b * 3 * N_PIX;

    __syncthreads();

    for (int tile = 0; tile < 98; ++tile) {
        const int n0 = (bx * 98 + tile) * 64;
        // ---- Stage 1 ----
        {
            int n = n0 + s1r;
            float x0 = images[imgbase + n];
            float x1 = images[imgbase + N_PIX + n];
            float x2 = images[imgbase + 2 * N_PIX + n];
            s8v v0, v1;
            #pragma unroll
            for (int j4 = 0; j4 < 4; ++j4) {
                f4v w0 = *(const f4v*)&ws1[s1h + 4 * j4];
                f4v w1 = *(const f4v*)&ws1[128 + s1h + 4 * j4];
                f4v w2v = *(const f4v*)&ws1[256 + s1h + 4 * j4];
                f4v bb = *(const f4v*)&bs1[s1h + 4 * j4];
                #pragma unroll
                for (int j = 0; j < 4; ++j) {
                    float hv = fmaf(x0, w0[j], fmaf(x1, w1[j], fmaf(x2, w2v[j], bb[j])));
                    hv = fmaxf(hv, 0.f);
                    short bh = f2bf(hv);
                    int jj = j4 * 4 + j;
                    if (jj < 8) v0[jj] = bh; else v1[jj - 8] = bh;
                }
            }
            *(s8v*)(bufA + SWZ(s1r, s1h * 2)) = v0;
            *(s8v*)(bufA + SWZ(s1r, s1h * 2 + 16)) = v1;
            // eml2 tile -> bufC (raw bf16 copy)
            int cb = (t & 7) * 32;
            const char* src = (const char*)eml2 + ((size_t)(n0 + s1r) * 256 + cb);
            *(u4v*)(bufC + SWZ(s1r, cb)) = *(const u4v*)(src);
            *(u4v*)(bufC + SWZ(s1r, cb + 16)) = *(const u4v*)(src + 16);
        }
        __syncthreads();
        // ---- Stage 3: bufB = relu(bufA @ Wc + bufC + bias_c) ----
        {
            s8v a[4];
            #pragma unroll
            for (int ks = 0; ks < 4; ++ks)
                a[ks] = *(const s8v*)(bufA + SWZ(m0 + l15, ks * 64 + lg * 16));
            #pragma unroll
            for (int nt = 0; nt < 4; ++nt) {
                f4v acc = {0.f, 0.f, 0.f, 0.f};
                #pragma unroll
                for (int ks = 0; ks < 4; ++ks)
                    acc = __builtin_amdgcn_mfma_f32_16x16x32_bf16(a[ks], wc[nt][ks], acc, 0, 0, 0);
                int ncol = (nhalf * 4 + nt) * 16 + l15;
                #pragma unroll
                for (int r = 0; r < 4; ++r) {
                    int row = m0 + lg * 4 + r;
                    float v = acc[r] + bias3[nt]
                            + bf2f(*(const unsigned short*)(bufC + SWZ(row, ncol * 2)));
                    v = fmaxf(v, 0.f);
                    *(unsigned short*)(bufB + SWZ(row, ncol * 2)) = (unsigned short)f2bf(v);
                }
            }
        }
        __syncthreads();
        // ---- Stage 4: softplus(bufB @ w_ol2 + b_ol2), accumulate ----
        {
            s8v a[4];
            #pragma unroll
            for (int ks = 0; ks < 4; ++ks)
                a[ks] = *(const s8v*)(bufB + SWZ(m0 + l15, ks * 64 + lg * 16));
            #pragma unroll
            for (int i = 0; i < 2; ++i) {
                f4v acc = {0.f, 0.f, 0.f, 0.f};
                #pragma unroll
                for (int ks = 0; ks < 4; ++ks)
                    acc = __builtin_amdgcn_mfma_f32_16x16x32_bf16(a[ks], w2[i][ks], acc, 0, 0, 0);
                float s = 0.f;
                #pragma unroll
                for (int r = 0; r < 4; ++r) {
                    float xv = acc[r] + bias4[i];
                    float sp = fmaxf(xv, 0.f) + __logf(1.f + __expf(-fabsf(xv)));
                    s += sp;
                }
                if (i == 0) sp0 += s; else sp1 += s;
            }
        }
        __syncthreads();
    }

    // block reduction: columns
    sp0 += __shfl_xor(sp0, 16, 64); sp0 += __shfl_xor(sp0, 32, 64);
    sp1 += __shfl_xor(sp1, 16, 64); sp1 += __shfl_xor(sp1, 32, 64);
    if (l < 16) { red[w][l] = sp0; red[w][16 + l] = sp1; }
    __syncthreads();
    if (t < 64) {
        int half = t >> 5, j = t & 31;
        float s = red[half * 4 + 0][j] + red[half * 4 + 1][j]
                + red[half * 4 + 2][j] + red[half * 4 + 3][j];
        part[((size_t)b * 8 + bx) * 64 + t] = s;
    }
}

// ---------------------------------------------------------------------------
// K3: reduce partials + cls MLP (fp32)
// ---------------------------------------------------------------------------
__global__ __launch_bounds__(512) void k3_cls(
        const float* __restrict__ part,
        const float* __restrict__ w_cls1, const float* __restrict__ b_cls1,
        const float* __restrict__ w_cls2, const float* __restrict__ b_cls2,
        float* __restrict__ out) {
    __shared__ float es[32 * 64];
    __shared__ float hid[32 * 128];
    int t = threadIdx.x;
    #pragma unroll
    for (int q = 0; q < 4; ++q) {
        int idx = t + q * 512;                 // b*64+e
        float s = 0.f;
        #pragma unroll
        for (int x = 0; x < 8; ++x) s += part[(size_t)(idx >> 6) * 512 + x * 64 + (idx & 63)];
        es[idx] = s;
    }
    __syncthreads();
    #pragma unroll
    for (int q = 0; q < 8; ++q) {
        int idx = t + q * 512;                 // b*128+h
        int bi = idx >> 7, h = idx & 127;
        float s = b_cls1[h];
        #pragma unroll
        for (int e = 0; e < 64; ++e) s = fmaf(es[bi * 64 + e], w_cls1[e * 128 + h], s);
        hid[idx] = fmaxf(s, 0.f);
    }
    __syncthreads();
    if (t < 320) {
        int bi = t / 10, o = t % 10;
        float s = b_cls2[o];
        for (int h = 0; h < 128; ++h) s = fmaf(hid[bi * 128 + h], w_cls2[h * 10 + o], s);
        out[t] = s;
    }
}

extern "C" void kernel_launch(void* const* d_in, const int* in_sizes, int n_in,
                              void* d_out, int out_size, void* d_ws, size_t ws_size,
                              hipStream_t stream) {
    (void)in_sizes; (void)n_in; (void)out_size; (void)ws_size;
    const float* images = (const float*)d_in[0];
    const float* w_obs1 = (const float*)d_in[1];
    const float* b_obs1 = (const float*)d_in[2];
    const float* w_obs2 = (const float*)d_in[3];
    const float* b_obs2 = (const float*)d_in[4];
    const float* w_loc1 = (const float*)d_in[5];
    const float* b_loc1 = (const float*)d_in[6];
    const float* w_loc2 = (const float*)d_in[7];
    const float* b_loc2 = (const float*)d_in[8];
    const float* w_ol1  = (const float*)d_in[9];
    const float* b_ol1  = (const float*)d_in[10];
    const float* w_ol2  = (const float*)d_in[11];
    const float* b_ol2  = (const float*)d_in[12];
    const float* w_cls1 = (const float*)d_in[13];
    const float* b_cls1 = (const float*)d_in[14];
    const float* w_cls2 = (const float*)d_in[15];
    const float* b_cls2 = (const float*)d_in[16];

    char* ws = (char*)d_ws;
    float* part           = (float*)(ws);                  // 32*8*64*4   = 65536
    float* biasc          = (float*)(ws + 65536);          // 128*4       = 512
    unsigned short* Wct   = (unsigned short*)(ws + 66048); // 128*128*2   = 32768
    unsigned short* wol2t = (unsigned short*)(ws + 98816); // 64*128*2    = 16384
    unsigned short* eml2  = (unsigned short*)(ws + 115200);// 50176*128*2 = 12845056

    hipLaunchKernelGGL(k0_weights, dim3(97), dim3(256), 0, stream,
                       w_obs2, b_obs2, w_ol1, b_ol1, w_ol2, Wct, wol2t, biasc);
    hipLaunchKernelGGL(k1_loc, dim3(196), dim3(256), 0, stream,
                       w_loc1, b_loc1, w_loc2, b_loc2, w_ol1, eml2);
    hipLaunchKernelGGL(k2_main, dim3(8, 32), dim3(512), 0, stream,
                       images, w_obs1, b_obs1, Wct, biasc, wol2t, b_ol2, eml2, part);
    hipLaunchKernelGGL(k3_cls, dim3(1), dim3(512), 0, stream,
                       part, w_cls1, b_cls1, w_cls2, b_cls2, (float*)d_out);
}